// Round 5
// baseline (189.322 us; speedup 1.0000x reference)
//
#include <hip/hip_runtime.h>

typedef __bf16 bf16;
typedef __bf16 bf16x8 __attribute__((ext_vector_type(8)));
typedef __bf16 bf16x4 __attribute__((ext_vector_type(4)));
typedef float  f32x4  __attribute__((ext_vector_type(4)));

#define NND   2048      // nodes
#define DIMD  16        // embedding dim
#define NBB   8         // batch
#define NPADC 640       // padded panel rows (>= 528, mult of 128)
#define KEXP  3328      // expanded K: 208 ki-chunks * 16 d (198 real + bias + zeros)
#define MTOT  16384     // B*N

__device__ __forceinline__ float sigf(float v) { return 1.f / (1.f + __expf(-v)); }

__device__ __forceinline__ void gl_lds16(const bf16* g, bf16* l) {
  __builtin_amdgcn_global_load_lds(
      (const __attribute__((address_space(1))) void*)g,
      (__attribute__((address_space(3))) void*)l, 16, 0, 0);
}

// ---------------------------------------------------------------
// K1: S = softmax(relu(E E^T)) rows, bf16 out. 8 rows per block.
// ---------------------------------------------------------------
__global__ __launch_bounds__(256)
void adj_kernel(const float* __restrict__ E, bf16* __restrict__ Sbf) {
  int r0 = blockIdx.x * 8;
  int t = threadIdx.x;
  int lane = t & 63, w = t >> 6;
  __shared__ float Et[16][2048];
  __shared__ float red[2][4][8];
  for (int i = t; i < 8192; i += 256) {
    f32x4 v4 = *(const f32x4*)&E[(size_t)i * 4];
    int n = i >> 2, d0 = (i & 3) << 2;
    Et[d0 + 0][n] = v4.x; Et[d0 + 1][n] = v4.y;
    Et[d0 + 2][n] = v4.z; Et[d0 + 3][n] = v4.w;
  }
  __syncthreads();
  float er[8][16];
#pragma unroll
  for (int r = 0; r < 8; ++r)
#pragma unroll
    for (int d = 0; d < 16; ++d) er[r][d] = Et[d][r0 + r];

  float v[8][8];
  float mx[8];
#pragma unroll
  for (int r = 0; r < 8; ++r) mx[r] = 0.f;
#pragma unroll
  for (int j = 0; j < 8; ++j) {
    int c = t + j * 256;
    float ec[16];
#pragma unroll
    for (int d = 0; d < 16; ++d) ec[d] = Et[d][c];
#pragma unroll
    for (int r = 0; r < 8; ++r) {
      float s = 0.f;
#pragma unroll
      for (int d = 0; d < 16; ++d) s += er[r][d] * ec[d];
      s = fmaxf(s, 0.f);
      v[r][j] = s;
      mx[r] = fmaxf(mx[r], s);
    }
  }
#pragma unroll
  for (int o = 32; o > 0; o >>= 1)
#pragma unroll
    for (int r = 0; r < 8; ++r) mx[r] = fmaxf(mx[r], __shfl_xor(mx[r], o, 64));
  if (lane == 0)
#pragma unroll
    for (int r = 0; r < 8; ++r) red[0][w][r] = mx[r];
  __syncthreads();
#pragma unroll
  for (int r = 0; r < 8; ++r)
    mx[r] = fmaxf(fmaxf(red[0][0][r], red[0][1][r]), fmaxf(red[0][2][r], red[0][3][r]));
  float sm[8];
#pragma unroll
  for (int r = 0; r < 8; ++r) sm[r] = 0.f;
#pragma unroll
  for (int j = 0; j < 8; ++j)
#pragma unroll
    for (int r = 0; r < 8; ++r) { v[r][j] = __expf(v[r][j] - mx[r]); sm[r] += v[r][j]; }
#pragma unroll
  for (int o = 32; o > 0; o >>= 1)
#pragma unroll
    for (int r = 0; r < 8; ++r) sm[r] += __shfl_xor(sm[r], o, 64);
  if (lane == 0)
#pragma unroll
    for (int r = 0; r < 8; ++r) red[1][w][r] = sm[r];
  __syncthreads();
#pragma unroll
  for (int r = 0; r < 8; ++r) {
    float inv = 1.f / (red[1][0][r] + red[1][1][r] + red[1][2][r] + red[1][3][r]);
#pragma unroll
    for (int j = 0; j < 8; ++j)
      Sbf[(size_t)(r0 + r) * NND + t + j * 256] = (bf16)(v[r][j] * inv);
  }
}

// ---------------------------------------------------------------
// K2: pack concat(x,state) transposed: XT[(b*66+c)][n] bf16.
// Also writes the x-rows (c<2) of candT.
// ---------------------------------------------------------------
__global__ __launch_bounds__(256)
void pack_xs_kernel(const float* __restrict__ x, const float* __restrict__ state,
                    bf16* __restrict__ XT, bf16* __restrict__ candT) {
  int b  = blockIdx.x >> 5;
  int n0 = (blockIdx.x & 31) * 64;
  int t  = threadIdx.x;
  __shared__ float tile[66][65];
  for (int idx = t; idx < 66 * 64; idx += 256) {
    int nn = idx / 66;
    int c  = idx - nn * 66;
    int bn = (b << 11) + n0 + nn;
    float v = (c < 2) ? x[bn * 2 + c] : state[(bn << 6) + c - 2];
    tile[c][nn] = v;
  }
  __syncthreads();
  for (int idx = t; idx < 66 * 64; idx += 256) {
    int c = idx >> 6;
    int nn = idx & 63;
    bf16 v = (bf16)tile[c][nn];
    size_t off = (size_t)(b * 66 + c) * NND + n0 + nn;
    XT[off] = v;
    if (c < 2) candT[off] = v;
  }
}

// ---------------------------------------------------------------
// K3: graph GEMM partials, 128x128 tile, BK=64, swizzled LDS (T2/rule21):
// linear gl_lds dest + XOR'd global source col-group + XOR'd ds_read.
// P[z][c][n] = sum_{k in z-quarter} A[n][k]*BT[c][k]
// grid = (2048/128, NPADC/128, 4), 256 thr
// ---------------------------------------------------------------
__global__ __launch_bounds__(256)
void gemm_kernel(const bf16* __restrict__ A, const bf16* __restrict__ BT,
                 float* __restrict__ P) {
  __shared__ bf16 As[2][128 * 64];
  __shared__ bf16 Bs[2][128 * 64];
  int t = threadIdx.x;
  int m0 = blockIdx.x * 128;
  int c0 = blockIdx.y * 128;
  int z  = blockIdx.z;
  int lane = t & 63;
  int w = t >> 6;
  int wr = w >> 1, wc = w & 1;
  int row16 = lane & 15;
  int kq = (lane >> 4) << 3;

  f32x4 acc[4][4] = {};
  int kbase = z * 512;

  auto stage = [&](int k0, int bb) {
#pragma unroll
    for (int i = 0; i < 4; ++i) {
      int s = i * 256 + t;
      int row = s >> 3;
      int g = ((s & 7) ^ (row & 7)) << 3;        // pre-swizzled source col
      gl_lds16(A  + (size_t)(m0 + row) * NND + k0 + g, &As[bb][s * 8]);
      gl_lds16(BT + (size_t)(c0 + row) * NND + k0 + g, &Bs[bb][s * 8]);
    }
  };

  stage(kbase, 0);
  __syncthreads();

  int buf = 0;
  for (int s = 0; s < 8; ++s) {
    if (s < 7) stage(kbase + (s + 1) * 64, buf ^ 1);
#pragma unroll
    for (int kk2 = 0; kk2 < 64; kk2 += 32) {
      int kcg = (kk2 + kq) >> 3;
      bf16x8 a[4], bfr[4];
#pragma unroll
      for (int mi = 0; mi < 4; ++mi) {
        int row = wr * 64 + mi * 16 + row16;
        a[mi] = *(const bf16x8*)&As[buf][row * 64 + ((kcg ^ (row & 7)) << 3)];
      }
#pragma unroll
      for (int ni = 0; ni < 4; ++ni) {
        int row = wc * 64 + ni * 16 + row16;
        bfr[ni] = *(const bf16x8*)&Bs[buf][row * 64 + ((kcg ^ (row & 7)) << 3)];
      }
#pragma unroll
      for (int mi = 0; mi < 4; ++mi)
#pragma unroll
        for (int ni = 0; ni < 4; ++ni)
          acc[mi][ni] = __builtin_amdgcn_mfma_f32_16x16x32_bf16(a[mi], bfr[ni], acc[mi][ni], 0, 0, 0);
    }
    __syncthreads();
    buf ^= 1;
  }

#pragma unroll
  for (int mi = 0; mi < 4; ++mi)
#pragma unroll
    for (int ni = 0; ni < 4; ++ni) {
      int nb = m0 + wr * 64 + mi * 16 + ((lane >> 4) << 2);
      int oc = c0 + wc * 64 + ni * 16 + (lane & 15);
      *(f32x4*)&P[((size_t)z * NPADC + oc) * NND + nb] = acc[mi][ni];
    }
}

// ---------------------------------------------------------------
// K3b: reduce 4 partials -> bf16.
// ---------------------------------------------------------------
__global__ __launch_bounds__(256)
void reduce_kernel(const float* __restrict__ P, bf16* __restrict__ Y) {
  size_t i = ((size_t)blockIdx.x * 256 + threadIdx.x) * 4;
  const size_t PL = (size_t)NPADC * NND;
  f32x4 s = *(const f32x4*)&P[i];
  s += *(const f32x4*)&P[PL + i];
  s += *(const f32x4*)&P[2 * PL + i];
  s += *(const f32x4*)&P[3 * PL + i];
  *(bf16x4*)&Y[i] = __builtin_convertvector(s, bf16x4);
}

// ---------------------------------------------------------------
// K4: prep (merged).  B'T[o][ki*16+d] = Wp[d][ki/66][ki%66][o]
// ---------------------------------------------------------------
__global__ __launch_bounds__(256)
void prep_w_kernel(const float* __restrict__ WpG, const float* __restrict__ BpG,
                   const float* __restrict__ WpU, const float* __restrict__ BpU,
                   bf16* __restrict__ BTg, bf16* __restrict__ BTu) {
  __shared__ float tile[64][65];
  int which = blockIdx.y;
  const float* Wp; const float* Bp; bf16* BT; int ncols, o0;
  if (which < 2) { Wp = WpG; Bp = BpG; BT = BTg; ncols = 128; o0 = which * 64; }
  else           { Wp = WpU; Bp = BpU; BT = BTu; ncols = 64;  o0 = 0; }
  int k0 = blockIdx.x * 64;
  int t = threadIdx.x;
  for (int idx = t; idx < 4096; idx += 256) {
    int kr = idx >> 6, oc = idx & 63;
    int kp = k0 + kr;
    int ki = kp >> 4, d = kp & 15;
    float v;
    if (ki < 198) {
      int kc3 = ki / 66;
      int i = ki - kc3 * 66;
      v = Wp[(size_t)((d * 3 + kc3) * 66 + i) * ncols + o0 + oc];
    } else if (ki == 198) {
      v = Bp[d * ncols + o0 + oc];
    } else {
      v = 0.f;
    }
    tile[kr][oc] = v;
  }
  __syncthreads();
  for (int idx = t; idx < 4096; idx += 256) {
    int orow = idx >> 6, kc = idx & 63;
    BT[(size_t)(o0 + orow) * KEXP + k0 + kc] = (bf16)tile[kc][orow];
  }
}

// ---------------------------------------------------------------
// K5: expansion GEMM partials, 128xTN tile, BK=64, z=4 K-split.
// A'[bn][ki*16+d] = xg(bn,ki)*E[n][d] built in LDS (swizzled ds_write).
// B staged via pre-swizzled gl_lds. P[z][oc][bn].
// grid = (128, 1, 4), 256 thr
// ---------------------------------------------------------------
template<int TN>
__global__ __launch_bounds__(256)
void wgemm_kernel(const bf16* __restrict__ XTsrc, const bf16* __restrict__ Y1src,
                  const bf16* __restrict__ Y2src, const float* __restrict__ E,
                  const bf16* __restrict__ BT, float* __restrict__ P) {
  constexpr int MI  = (TN == 128) ? 4 : 2;   // m-frags per wave
  constexpr int NBI = TN / 32;               // B stage issues
  __shared__ bf16 As[2][128 * 64];
  __shared__ bf16 Bs[2][TN * 64];
  int t = threadIdx.x;
  int m0 = blockIdx.x * 128;
  int z  = blockIdx.z;
  int r = t & 127, kh = t >> 7;
  int bn = m0 + r, bidx = bn >> 11, n = bn & 2047;
  float e[16];
  {
    const f32x4* ep = (const f32x4*)(E + n * 16);
    f32x4 q0 = ep[0], q1 = ep[1], q2 = ep[2], q3 = ep[3];
    e[0]=q0.x; e[1]=q0.y; e[2]=q0.z; e[3]=q0.w;
    e[4]=q1.x; e[5]=q1.y; e[6]=q1.z; e[7]=q1.w;
    e[8]=q2.x; e[9]=q2.y; e[10]=q2.z; e[11]=q2.w;
    e[12]=q3.x; e[13]=q3.y; e[14]=q3.z; e[15]=q3.w;
  }
  int lane = t & 63, w = t >> 6;
  int wr = (TN == 128) ? (w >> 1) : w;
  int wc = (TN == 128) ? (w & 1) : 0;
  int row16 = lane & 15;
  int kq = (lane >> 4) << 3;
  int wrM = wr * (MI * 16);

  f32x4 acc[MI][4] = {};
  const int kbase = z * (KEXP / 4);          // 832

  auto loadx = [&](int ki) -> float {
    if (ki < 66)  return (float)XTsrc[(size_t)(bidx * 66 + ki) * NND + n];
    if (ki < 132) return (float)Y1src[(size_t)(bidx * 66 + ki - 66) * NND + n];
    if (ki < 198) {
      size_t off = (size_t)(bidx * 66 + ki - 132) * NND + n;
      return 2.f * (float)Y2src[off] - (float)XTsrc[off];
    }
    return (ki == 198) ? 1.f : 0.f;
  };
  auto expand = [&](int bb, float xv0, float xv1) {
#pragma unroll
    for (int p = 0; p < 4; ++p) {
      float xa = (p < 2) ? xv0 : xv1;
      const int eb = (p & 1) * 8;
      bf16x8 pk;
#pragma unroll
      for (int j = 0; j < 8; ++j) pk[j] = (bf16)(xa * e[eb + j]);
      int gidx = ((kh * 4 + p) ^ (r & 7)) << 3;
      *(bf16x8*)&As[bb][r * 64 + gidx] = pk;
    }
  };
  auto stageB = [&](int k0, int bb) {
#pragma unroll
    for (int i = 0; i < NBI; ++i) {
      int s = i * 256 + t;
      int row = s >> 3;
      int g = ((s & 7) ^ (row & 7)) << 3;
      gl_lds16(BT + (size_t)row * KEXP + k0 + g, &Bs[bb][s * 8]);
    }
  };
  auto mstep = [&](int bb) {
#pragma unroll
    for (int kk2 = 0; kk2 < 64; kk2 += 32) {
      int kcg = (kk2 + kq) >> 3;
      bf16x8 af[MI], bfg[4];
#pragma unroll
      for (int mi = 0; mi < MI; ++mi) {
        int row = wrM + mi * 16 + row16;
        af[mi] = *(const bf16x8*)&As[bb][row * 64 + ((kcg ^ (row & 7)) << 3)];
      }
#pragma unroll
      for (int ni = 0; ni < 4; ++ni) {
        int row = wc * 64 + ni * 16 + row16;
        bfg[ni] = *(const bf16x8*)&Bs[bb][row * 64 + ((kcg ^ (row & 7)) << 3)];
      }
#pragma unroll
      for (int mi = 0; mi < MI; ++mi)
#pragma unroll
        for (int ni = 0; ni < 4; ++ni)
          acc[mi][ni] = __builtin_amdgcn_mfma_f32_16x16x32_bf16(af[mi], bfg[ni], acc[mi][ni], 0, 0, 0);
    }
  };

  // prologue: step 0 into buf 0
  {
    int ki0 = (kbase >> 4) + kh * 2;
    float xv0 = loadx(ki0), xv1 = loadx(ki0 + 1);
    stageB(kbase, 0);
    expand(0, xv0, xv1);
  }
  __syncthreads();

  int buf = 0;
  for (int s = 0; s < 13; ++s) {
    float xv0 = 0.f, xv1 = 0.f;
    if (s < 12) {
      int k1 = kbase + (s + 1) * 64;
      stageB(k1, buf ^ 1);
      int ki0 = (k1 >> 4) + kh * 2;
      xv0 = loadx(ki0); xv1 = loadx(ki0 + 1);
    }
    mstep(buf);
    __syncthreads();                 // MFMA reads done; gl_lds(buf^1) drained; xv in regs
    if (s < 12) {
      expand(buf ^ 1, xv0, xv1);
      __syncthreads();               // As[buf^1] visible
    }
    buf ^= 1;
  }

#pragma unroll
  for (int mi = 0; mi < MI; ++mi)
#pragma unroll
    for (int ni = 0; ni < 4; ++ni) {
      int nb = m0 + wrM + mi * 16 + ((lane >> 4) << 2);
      int oc = wc * 64 + ni * 16 + (lane & 15);
      *(f32x4*)&P[((size_t)z * TN + oc) * MTOT + nb] = acc[mi][ni];
    }
}

// ---------------------------------------------------------------
// K6: gate epilogue (z=4 partials).
// ---------------------------------------------------------------
__global__ __launch_bounds__(256)
void gate_epi(const float* __restrict__ P, const float* __restrict__ state,
              float* __restrict__ zT, bf16* __restrict__ candT) {
  __shared__ float st[64][65];
  int bn0 = blockIdx.x * 64;
  int t = threadIdx.x;
#pragma unroll
  for (int i = 0; i < 16; ++i) {
    int e = i * 256 + t;
    int bnr = e >> 6, hc = e & 63;
    st[hc][bnr] = state[(size_t)(bn0 + bnr) * 64 + hc];
  }
  __syncthreads();
#pragma unroll
  for (int i = 0; i < 4; ++i) {
    int pr = i * 256 + t;
    int h = pr >> 4, bl = (pr & 15) * 4;
    int bn = bn0 + bl;
    f32x4 zs = {0.f, 0.f, 0.f, 0.f}, rs = {0.f, 0.f, 0.f, 0.f};
#pragma unroll
    for (int zz = 0; zz < 4; ++zz) {
      zs += *(const f32x4*)&P[((size_t)zz * 128 + h) * MTOT + bn];
      rs += *(const f32x4*)&P[((size_t)zz * 128 + 64 + h) * MTOT + bn];
    }
    f32x4 zv; bf16x4 cv;
#pragma unroll
    for (int j = 0; j < 4; ++j) {
      zv[j] = sigf(zs[j]);
      cv[j] = (bf16)(sigf(rs[j]) * st[h][bl + j]);
    }
    *(f32x4*)&zT[(size_t)h * MTOT + bn] = zv;
    int b = bn >> 11, n = bn & 2047;
    *(bf16x4*)&candT[(size_t)(b * 66 + 2 + h) * NND + n] = cv;
  }
}

// ---------------------------------------------------------------
// K7: update epilogue (z=4 partials).
// ---------------------------------------------------------------
__global__ __launch_bounds__(256)
void update_epi(const float* __restrict__ P, const float* __restrict__ state,
                const float* __restrict__ zT, float* __restrict__ out) {
  __shared__ float st[64][65];
  int bn0 = blockIdx.x * 64;
  int t = threadIdx.x;
#pragma unroll
  for (int i = 0; i < 16; ++i) {
    int e = i * 256 + t;
    int bnr = e >> 6, oc = e & 63;
    st[oc][bnr] = state[(size_t)(bn0 + bnr) * 64 + oc];
  }
  __syncthreads();
#pragma unroll
  for (int i = 0; i < 4; ++i) {
    int pr = i * 256 + t;
    int o = pr >> 4, bl = (pr & 15) * 4;
    int bn = bn0 + bl;
    f32x4 ps = {0.f, 0.f, 0.f, 0.f};
#pragma unroll
    for (int zz = 0; zz < 4; ++zz)
      ps += *(const f32x4*)&P[((size_t)zz * 64 + o) * MTOT + bn];
    f32x4 zv = *(const f32x4*)&zT[(size_t)o * MTOT + bn];
#pragma unroll
    for (int j = 0; j < 4; ++j) {
      float hc = tanhf(ps[j]);
      float s0 = st[o][bl + j];
      st[o][bl + j] = (1.f - zv[j]) * s0 + zv[j] * hc;
    }
  }
  __syncthreads();
#pragma unroll
  for (int i = 0; i < 16; ++i) {
    int e = i * 256 + t;
    int bnr = e >> 6, oc = e & 63;
    out[(size_t)(bn0 + bnr) * 64 + oc] = st[oc][bnr];
  }
}

// ---------------------------------------------------------------
extern "C" void kernel_launch(void* const* d_in, const int* in_sizes, int n_in,
                              void* d_out, int out_size, void* d_ws, size_t ws_size,
                              hipStream_t stream) {
  const float* x     = (const float*)d_in[0];
  const float* state = (const float*)d_in[1];
  const float* E     = (const float*)d_in[2];
  const float* WpG   = (const float*)d_in[3];
  const float* BpG   = (const float*)d_in[4];
  const float* WpU   = (const float*)d_in[5];
  const float* BpU   = (const float*)d_in[6];
  float* out = (float*)d_out;

  char* p = (char*)d_ws;
  bf16*  Sbf   = (bf16*)p;  p += (size_t)NND * NND * 2;       // 8 MB
  bf16*  XT    = (bf16*)p;  p += (size_t)NPADC * NND * 2;     // 2.5 MB
  bf16*  candT = (bf16*)p;  p += (size_t)NPADC * NND * 2;     // 2.5 MB
  bf16*  Y1bf  = (bf16*)p;  p += (size_t)NPADC * NND * 2;     // 2.5 MB
  bf16*  Y2bf  = (bf16*)p;  p += (size_t)NPADC * NND * 2;     // 2.5 MB
  float* zT    = (float*)p; p += (size_t)64 * MTOT * 4;       // 4 MB
  bf16*  BTg   = (bf16*)p;  p += (size_t)128 * KEXP * 2;      // 832 KB
  bf16*  BTu   = (bf16*)p;  p += (size_t)64 * KEXP * 2;       // 416 KB
  float* P     = (float*)p; p += (size_t)4 * 128 * MTOT * 4;  // 33.6 MB (covers graph 21 MB too)

  dim3 b256(256);
  dim3 gemmGrid(NND / 128, NPADC / 128, 4);
  int redGrid = NPADC * NND / 1024;

  prep_w_kernel<<<dim3(KEXP / 64, 3), b256, 0, stream>>>(WpG, BpG, WpU, BpU, BTg, BTu);
  adj_kernel<<<256, b256, 0, stream>>>(E, Sbf);
  pack_xs_kernel<<<256, b256, 0, stream>>>(x, state, XT, candT);

  gemm_kernel<<<gemmGrid, b256, 0, stream>>>(Sbf, XT, P);
  reduce_kernel<<<redGrid, b256, 0, stream>>>(P, Y1bf);
  gemm_kernel<<<gemmGrid, b256, 0, stream>>>(Sbf, Y1bf, P);
  reduce_kernel<<<redGrid, b256, 0, stream>>>(P, Y2bf);
  wgemm_kernel<128><<<dim3(128, 1, 4), b256, 0, stream>>>(XT, Y1bf, Y2bf, E, BTg, P);
  gate_epi<<<MTOT / 64, b256, 0, stream>>>(P, state, zT, candT);

  gemm_kernel<<<gemmGrid, b256, 0, stream>>>(Sbf, candT, P);
  reduce_kernel<<<redGrid, b256, 0, stream>>>(P, Y1bf);
  gemm_kernel<<<gemmGrid, b256, 0, stream>>>(Sbf, Y1bf, P);
  reduce_kernel<<<redGrid, b256, 0, stream>>>(P, Y2bf);
  wgemm_kernel<64><<<dim3(128, 1, 4), b256, 0, stream>>>(candT, Y1bf, Y2bf, E, BTu, P);
  update_epi<<<MTOT / 64, b256, 0, stream>>>(P, state, zT, out);
}